// Round 1
// baseline (2800.539 us; speedup 1.0000x reference)
//
#include <hip/hip_runtime.h>
#include <hip/hip_bf16.h>

// LSTM decoder: L=2, B=64, T=512, H=IN=512, gates G=2048 (i,f,g,o).
// Round 7: layer-decoupled persistent kernel.
//  - per-layer 64-block barriers (two padded counter sets) instead of one
//    128-block lockstep barrier: each layer steps at its own chain rate.
//  - h0 exchange deepened to a 4-slot ring; L0 flow-control guard
//    cntL1 >= 64*(t-3) before overwriting slot t&3 (exactly sufficient,
//    deadlock-free: L0-blocked => L1 runnable and vice versa).
//  - layer-1 ih (Ax coherent load + 16 MFMA) moved OFF the critical path
//    into the post-arrive overlap (mirrors layer-0's x-ih overlap); gated
//    by cntL0 >= 64*(t+2), normally already satisfied (L0 leads 2-3).
//  - x-row reuse ordering preserved: L1's out-row-t write is causally
//    after L0's x(t) read via the h0(t) dependency gate.
// Numerics = validated rounds 2-5: ih single bf16, hh hi+lo W x hi+lo h.

#define TT 512

using short8 = __attribute__((ext_vector_type(8))) short;
using f32x4  = __attribute__((ext_vector_type(4))) float;

__device__ __forceinline__ short f2bf(float f) {
  unsigned u = __float_as_uint(f);
  u = (u + 0x7fffu + ((u >> 16) & 1u)) >> 16;  // RNE
  return (short)u;
}
__device__ __forceinline__ float bf2f(short s) {
  return __uint_as_float(((unsigned)(unsigned short)s) << 16);
}
__device__ __forceinline__ float sigf(float x) { return 1.f / (1.f + __expf(-x)); }
__device__ __forceinline__ float tanh_(float x) { return 1.f - 2.f / (__expf(2.f * x) + 1.f); }

// 8 coherent 16B loads, NO wait (caller ties the waitcnt to the results).
__device__ __forceinline__ void ld8_nw(short8* d,
    const short* p0, const short* p1, const short* p2, const short* p3,
    const short* p4, const short* p5, const short* p6, const short* p7) {
  asm volatile(
      "global_load_dwordx4 %0, %8, off sc0 sc1\n\t"
      "global_load_dwordx4 %1, %9, off sc0 sc1\n\t"
      "global_load_dwordx4 %2, %10, off sc0 sc1\n\t"
      "global_load_dwordx4 %3, %11, off sc0 sc1\n\t"
      "global_load_dwordx4 %4, %12, off sc0 sc1\n\t"
      "global_load_dwordx4 %5, %13, off sc0 sc1\n\t"
      "global_load_dwordx4 %6, %14, off sc0 sc1\n\t"
      "global_load_dwordx4 %7, %15, off sc0 sc1"
      : "=&v"(d[0]), "=&v"(d[1]), "=&v"(d[2]), "=&v"(d[3]),
        "=&v"(d[4]), "=&v"(d[5]), "=&v"(d[6]), "=&v"(d[7])
      : "v"(p0), "v"(p1), "v"(p2), "v"(p3),
        "v"(p4), "v"(p5), "v"(p6), "v"(p7)
      : "memory");
}

// tie a waitcnt (or nothing) to 8 loaded fragments so no use precedes it
#define TIE8(A, CNT)                                                        \
  asm volatile(CNT : "+v"(A[0]), "+v"(A[1]), "+v"(A[2]), "+v"(A[3]),        \
                     "+v"(A[4]), "+v"(A[5]), "+v"(A[6]), "+v"(A[7])         \
               ::"memory")

// coherent 2B store (write-through to device coherence point)
__device__ __forceinline__ void stc_short(short* p, short v) {
  asm volatile("global_store_short %0, %1, off sc0 sc1"
               :: "v"(p), "v"((int)v) : "memory");
}

// ---- x fp32 [64][512][512] -> bf16 in first half of each out row ----
__global__ __launch_bounds__(256) void conv_x(const float* __restrict__ x,
                                              short* __restrict__ xo) {
  size_t g = (size_t)blockIdx.x * 256 + threadIdx.x;  // 2,097,152
  size_t i = g * 8;
  float4 v0 = *(const float4*)(x + i);
  float4 v1 = *(const float4*)(x + i + 4);
  short8 r;
  r[0] = f2bf(v0.x); r[1] = f2bf(v0.y); r[2] = f2bf(v0.z); r[3] = f2bf(v0.w);
  r[4] = f2bf(v1.x); r[5] = f2bf(v1.y); r[6] = f2bf(v1.z); r[7] = f2bf(v1.w);
  *(short8*)(xo + (i >> 9) * 1024 + (i & 511)) = r;
}

// ---- W pack: per-block contiguous LDS image (49152 shorts per (l,j8)) ----
__global__ __launch_bounds__(256) void conv_w(const float* __restrict__ Wih,
                                              const float* __restrict__ Whh,
                                              short* __restrict__ wp) {
  int g = blockIdx.x * 256 + threadIdx.x;  // 0..786431
  int l = g / 393216;
  int rem = g % 393216;
  int j8 = rem / 6144;
  int q8 = rem % 6144;
  int s, hl, bt, c, lane;
  if (q8 < 2048) {
    s = 0; hl = 0;
    int seg = q8 >> 6; bt = seg >> 4; c = seg & 15; lane = q8 & 63;
  } else {
    int q = q8 - 2048;
    s = 1;
    int seg = q >> 6; bt = seg >> 5; c = (seg >> 1) & 15; hl = seg & 1;
    lane = q & 63;
  }
  int r = lane & 15;
  int gg = r >> 2, jj = r & 3;
  int R = gg * 512 + j8 * 8 + bt * 4 + jj;
  int k = c * 32 + (lane >> 4) * 8;
  const float* src = (s ? Whh : Wih) + ((size_t)(l * 2048 + R)) * 512 + k;
  short8 o;
#pragma unroll
  for (int e = 0; e < 8; ++e) {
    float v = src[e];
    short hi = f2bf(v);
    o[e] = hl ? f2bf(v - bf2f(hi)) : hi;
  }
  *(short8*)(wp + (size_t)g * 8) = o;
}

// ---- h0 -> ring slots (L0 init -> slot 3, L1 init -> slot 5) -------------
// hhi/hlo layout: [6 slots][k8=64][b=64][e=8]; slots 0-3 L0 ring, 4-5 L1.
__global__ __launch_bounds__(256) void init_state(const float* __restrict__ h0,
                                                  short* __restrict__ hhi,
                                                  short* __restrict__ hlo,
                                                  unsigned* __restrict__ bar) {
  int i = blockIdx.x * 256 + threadIdx.x;  // 0..65535 [l][b][j]
  int l = i >> 15, bj = i & 32767;
  int b = bj >> 9, j = bj & 511;
  float h = h0[i];
  short hi = f2bf(h);
  int slot = l ? 5 : 3;  // (-1) mod ring
  int o = slot * 32768 + (j >> 3) * 512 + b * 8 + (j & 7);
  hhi[o] = hi;
  hlo[o] = f2bf(h - bf2f(hi));
  if (blockIdx.x < 8) bar[blockIdx.x * 256 + threadIdx.x] = 0u;
}

// ---- split-phase fence-free per-layer barriers ----
__device__ __forceinline__ void garrive(unsigned* cnt, int tid, int slot) {
  __syncthreads();  // drains coherent h stores (vmcnt(0) before s_barrier)
  if (tid == 0)
    __hip_atomic_fetch_add(&cnt[slot * 32], 1u, __ATOMIC_RELAXED,
                           __HIP_MEMORY_SCOPE_AGENT);
}
__device__ __forceinline__ void gwait1(unsigned* c1, unsigned t1, int tid) {
  if (tid == 0) {
    for (;;) {
      unsigned s1 = 0;
#pragma unroll
      for (int r = 0; r < 32; ++r)
        s1 += __hip_atomic_load(&c1[r * 32], __ATOMIC_RELAXED,
                                __HIP_MEMORY_SCOPE_AGENT);
      if (s1 >= t1) break;
      __builtin_amdgcn_s_sleep(1);
    }
  }
  __syncthreads();
}
__device__ __forceinline__ void gwait2(unsigned* c1, unsigned t1,
                                       unsigned* c2, unsigned t2, int tid) {
  if (tid == 0) {
    for (;;) {
      unsigned s1 = 0, s2 = 0;
#pragma unroll
      for (int r = 0; r < 32; ++r) {
        s1 += __hip_atomic_load(&c1[r * 32], __ATOMIC_RELAXED,
                                __HIP_MEMORY_SCOPE_AGENT);
        s2 += __hip_atomic_load(&c2[r * 32], __ATOMIC_RELAXED,
                                __HIP_MEMORY_SCOPE_AGENT);
      }
      if (s1 >= t1 && s2 >= t2) break;
      __builtin_amdgcn_s_sleep(1);
    }
  }
  __syncthreads();
}

// ---- persistent LSTM ----------------------------------------------------
// grid 128 = [layer(2)][j8(64)]; block 512 = 8 waves (kq = wv&3, ah = wv>>2).
// dyn LDS 132096B: [0,98304) W image; [98304,..) float sG[4][32][66].
__global__ __launch_bounds__(512, 1) void lstm_persist(
    const short* __restrict__ wp, const float* __restrict__ c0,
    const float* __restrict__ bih, const float* __restrict__ bhh,
    short* __restrict__ hhi, short* __restrict__ hlo,
    unsigned* __restrict__ bar, float* __restrict__ out) {
  extern __shared__ char smem[];
  short* lw = (short*)smem;             // 49152 shorts
  float* sG = (float*)(smem + 98304);   // [kq][s][b] stride 66

  const int tid = threadIdx.x;
  const int layer = blockIdx.x >> 6;
  const int j8 = blockIdx.x & 63;
  const int bslot = blockIdx.x & 31;    // 2 blocks per padded counter
  unsigned* cntMy = bar + (layer << 10);        // own layer's 32 counters
  unsigned* cntOt = bar + ((layer ^ 1) << 10);  // other layer's
  const int wv = tid >> 6;
  const int kq = wv & 3;
  const int ah = wv >> 2;
  const int lane = tid & 63;
  const int m = lane & 15;
  const int koq = lane >> 4;
  const int cbase = kq << 2;

  {  // W slice -> LDS (one-time)
    const short* src = wp + (size_t)(layer * 64 + j8) * 49152;
    for (int i = tid; i < 6144; i += 512)
      *(short8*)(lw + i * 8) = *(const short8*)(src + i * 8);
  }

  const int sb = tid >> 3, sj = tid & 7;
  const int j = (j8 << 3) + sj;
  float creg = c0[layer * 32768 + sb * 512 + j];
  float hf = 0.f;
  float bsum[4];
#pragma unroll
  for (int g = 0; g < 4; ++g)
    bsum[g] = bih[layer * 2048 + g * 512 + j] + bhh[layer * 2048 + g * 512 + j];
  __syncthreads();

  const int br0 = ((ah * 2 + 0) << 4) + m;
  const int br1 = ((ah * 2 + 1) << 4) + m;
  const short* xo = (const short*)out;

  f32x4 acc[2][2];

  auto zacc = [&]() {
#pragma unroll
    for (int u = 0; u < 2; ++u)
#pragma unroll
      for (int v = 0; v < 2; ++v) acc[u][v] = f32x4{0.f, 0.f, 0.f, 0.f};
  };

#define PA(rX, cc, br) \
  ((rX) + ((((cbase + (cc)) << 2) + koq) << 9) + (br) * 8)

  // layer-0 ih for a given timestep from bf16 x rows (B-frags from LDS)
  auto ih_l0 = [&](int txt) {
#pragma unroll
    for (int cc = 0; cc < 4; ++cc) {
      const int c = cbase + cc;
      const int k = c * 32 + (koq << 3);
      short8 b0 = *(const short8*)(lw + c * 512 + lane * 8);
      short8 b1 = *(const short8*)(lw + (16 + c) * 512 + lane * 8);
#pragma unroll
      for (int it = 0; it < 2; ++it) {
        const int br = it ? br1 : br0;
        short8 a = *(const short8*)(xo + ((size_t)br * TT + txt) * 1024 + k);
        acc[0][it] = __builtin_amdgcn_mfma_f32_16x16x32_bf16(a, b0, acc[0][it], 0, 0, 0);
        acc[1][it] = __builtin_amdgcn_mfma_f32_16x16x32_bf16(a, b1, acc[1][it], 0, 0, 0);
      }
    }
  };

  // layer-1 ih from a coherent h0 ring slot (hi only; validated numerics)
  auto ih_l1 = [&](const short* ph) {
    short8 Ax[8];
    ld8_nw(Ax, PA(ph, 0, br0), PA(ph, 0, br1), PA(ph, 1, br0), PA(ph, 1, br1),
               PA(ph, 2, br0), PA(ph, 2, br1), PA(ph, 3, br0), PA(ph, 3, br1));
    TIE8(Ax, "s_waitcnt vmcnt(0)");
#pragma unroll
    for (int cc = 0; cc < 4; ++cc) {
      const int c = cbase + cc;
      short8 b0 = *(const short8*)(lw + c * 512 + lane * 8);
      short8 b1 = *(const short8*)(lw + (16 + c) * 512 + lane * 8);
#pragma unroll
      for (int it = 0; it < 2; ++it) {
        short8 a = Ax[cc * 2 + it];
        acc[0][it] = __builtin_amdgcn_mfma_f32_16x16x32_bf16(a, b0, acc[0][it], 0, 0, 0);
        acc[1][it] = __builtin_amdgcn_mfma_f32_16x16x32_bf16(a, b1, acc[1][it], 0, 0, 0);
      }
    }
  };

  // shared per-step body: hh (hi+lo), partial reduce, cell update, h store.
  // acc must already hold ih(t). rh/rl = read slot bases; slotOut = write slot.
  auto stepBody = [&](const short* rh, const short* rl, int slotOut, int t) {
    short8 Ah[8], Al[8];
    ld8_nw(Ah, PA(rh, 0, br0), PA(rh, 0, br1), PA(rh, 1, br0), PA(rh, 1, br1),
               PA(rh, 2, br0), PA(rh, 2, br1), PA(rh, 3, br0), PA(rh, 3, br1));
    ld8_nw(Al, PA(rl, 0, br0), PA(rl, 0, br1), PA(rl, 1, br0), PA(rl, 1, br1),
               PA(rl, 2, br0), PA(rl, 2, br1), PA(rl, 3, br0), PA(rl, 3, br1));
    TIE8(Ah, "s_waitcnt vmcnt(0)");
    TIE8(Al, "");

    // ---- hh: hi+lo W x hi+lo h (3 MFMA) ----
#pragma unroll
    for (int cc = 0; cc < 4; ++cc) {
      const int c = cbase + cc;
      short8 bh0 = *(const short8*)(lw + 16384 + (c * 2 + 0) * 512 + lane * 8);
      short8 bl0 = *(const short8*)(lw + 16384 + (c * 2 + 1) * 512 + lane * 8);
      short8 bh1 = *(const short8*)(lw + 16384 + ((16 + c) * 2 + 0) * 512 + lane * 8);
      short8 bl1 = *(const short8*)(lw + 16384 + ((16 + c) * 2 + 1) * 512 + lane * 8);
#pragma unroll
      for (int it = 0; it < 2; ++it) {
        short8 a = Ah[cc * 2 + it];
        short8 al = Al[cc * 2 + it];
        acc[0][it] = __builtin_amdgcn_mfma_f32_16x16x32_bf16(a, bh0, acc[0][it], 0, 0, 0);
        acc[0][it] = __builtin_amdgcn_mfma_f32_16x16x32_bf16(a, bl0, acc[0][it], 0, 0, 0);
        acc[0][it] = __builtin_amdgcn_mfma_f32_16x16x32_bf16(al, bh0, acc[0][it], 0, 0, 0);
        acc[1][it] = __builtin_amdgcn_mfma_f32_16x16x32_bf16(a, bh1, acc[1][it], 0, 0, 0);
        acc[1][it] = __builtin_amdgcn_mfma_f32_16x16x32_bf16(a, bl1, acc[1][it], 0, 0, 0);
        acc[1][it] = __builtin_amdgcn_mfma_f32_16x16x32_bf16(al, bh1, acc[1][it], 0, 0, 0);
      }
    }

    // ---- partials -> sG ----
#pragma unroll
    for (int bt = 0; bt < 2; ++bt)
#pragma unroll
      for (int it = 0; it < 2; ++it) {
        const int srow = bt * 16 + m;
        const int col = ((ah * 2 + it) << 4) + (koq << 2);
#pragma unroll
        for (int r = 0; r < 4; ++r)
          sG[(kq * 32 + srow) * 66 + col + r] = acc[bt][it][r];
      }
    __syncthreads();

    // ---- reduce + cell update ----
    {
      const int bt = sj >> 2, jl = sj & 3;
      float gv[4];
#pragma unroll
      for (int g = 0; g < 4; ++g) {
        const int s = bt * 16 + g * 4 + jl;
        gv[g] = sG[(0 * 32 + s) * 66 + sb] + sG[(1 * 32 + s) * 66 + sb] +
                sG[(2 * 32 + s) * 66 + sb] + sG[(3 * 32 + s) * 66 + sb] +
                bsum[g];
      }
      const float cn = sigf(gv[1]) * creg + sigf(gv[0]) * tanh_(gv[2]);
      const float hn = sigf(gv[3]) * tanh_(cn);
      creg = cn;
      hf = hn;
      const int ho = slotOut * 32768 + (j8 << 9) + tid;
      const short hb = f2bf(hn);
      stc_short(hhi + ho, hb);
      stc_short(hlo + ho, f2bf(hn - bf2f(hb)));
      if (layer)
        __builtin_nontemporal_store(hn, &out[((size_t)sb * 512 + t) * 512 + j]);
    }
  };

  if (layer == 0) {
    // -------- layer 0: own 64-block barrier; 4-slot h0 ring --------
    zacc();
    ih_l0(0);  // prologue: ih(t=0) from x (init_state h visible at launch)
    for (int t = 0; t < TT; ++t) {
      if (t >= 4)
        // own: all L0 stored h0(t-1). guard: all L1 arrived step t-4, so
        // their Ax read of h0(t-4) (slot t&3, about to be overwritten) done.
        gwait2(cntMy, (unsigned)(64 * t), cntOt, (unsigned)(64 * (t - 3)), tid);
      else if (t >= 1)
        gwait1(cntMy, (unsigned)(64 * t), tid);
      const int ps = (t + 3) & 3;  // slot of h0(t-1); t=0 -> 3 = init
      stepBody(hhi + ps * 32768, hlo + ps * 32768, t & 3, t);
      garrive(cntMy, tid, bslot);
      if (t + 1 < TT) {  // overlap next ih with others' wait
        zacc();
        ih_l0(t + 1);
      }
    }
  } else {
    // -------- layer 1: own 64-block barrier; ih in post-arrive overlap ----
    zacc();
    gwait1(cntOt, 64u, tid);  // L0 finished step 0 -> h0(0) in slot 0
    ih_l1(hhi + 0 * 32768);
    for (int t = 0; t < TT; ++t) {
      if (t >= 1) gwait1(cntMy, (unsigned)(64 * t), tid);
      const int ps = 4 + ((t + 1) & 1);  // slot of h1(t-1); t=0 -> 5 = init
      stepBody(hhi + ps * 32768, hlo + ps * 32768, 4 + (t & 1), t);
      garrive(cntMy, tid, bslot);
      if (t + 1 < TT) {
        // h0(t+1) needed: wait L0 finished step t+1 (normally already true),
        // then load Ax + ih in the shadow of other L1 blocks finishing t.
        gwait1(cntOt, (unsigned)(64 * (t + 2)), tid);
        zacc();
        ih_l1(hhi + ((t + 1) & 3) * 32768);
      }
    }
  }

  // finals from registers
  out[16777216 + layer * 32768 + sb * 512 + j] = hf;
  out[16777216 + 65536 + layer * 32768 + sb * 512 + j] = creg;
}

// ---- host ---------------------------------------------------------------

extern "C" void kernel_launch(void* const* d_in, const int* in_sizes, int n_in,
                              void* d_out, int out_size, void* d_ws,
                              size_t ws_size, hipStream_t stream) {
  const float* x = (const float*)d_in[0];
  const float* h0 = (const float*)d_in[1];
  const float* c0 = (const float*)d_in[2];
  const float* Wih = (const float*)d_in[3];
  const float* Whh = (const float*)d_in[4];
  const float* bih = (const float*)d_in[5];
  const float* bhh = (const float*)d_in[6];
  float* out = (float*)d_out;

  char* ws = (char*)d_ws;
  short* wp = (short*)(ws + 0);             // 12 MB  fragment-packed W images
  short* hhi = (short*)(ws + 12582912);     // 384 KB h hi [6 slots][k8][b][8]
  short* hlo = (short*)(ws + 12976128);     // 384 KB h lo
  unsigned* bar = (unsigned*)(ws + 13369344);  // 8 KB: 2 x 32 padded counters
  // total ws use: ~12.8 MB

  hipFuncSetAttribute(reinterpret_cast<const void*>(lstm_persist),
                      hipFuncAttributeMaxDynamicSharedMemorySize, 132096);

  conv_x<<<8192, 256, 0, stream>>>(x, (short*)out);
  conv_w<<<3072, 256, 0, stream>>>(Wih, Whh, wp);
  init_state<<<256, 256, 0, stream>>>(h0, hhi, hlo, bar);

  void* args[] = {(void*)&wp,  (void*)&c0,  (void*)&bih, (void*)&bhh,
                  (void*)&hhi, (void*)&hlo, (void*)&bar, (void*)&out};
  hipLaunchCooperativeKernel(reinterpret_cast<void*>(lstm_persist), dim3(128),
                             dim3(512), args, 132096, stream);
}